// Round 22
// baseline (38.469 us; speedup 1.0000x reference)
//
#include <hip/hip_runtime.h>
#include <stdint.h>

#define NE    7
#define DD    64
#define NDC   3
#define BLOCK 448       // 7 waves: wave w = expert w (one expert each)
#define ROWS  256       // rows per block; B = 1024*256
#define NFRAG 18

typedef __fp16   half8 __attribute__((ext_vector_type(8)));
typedef float    f32x4 __attribute__((ext_vector_type(4)));
typedef uint32_t u32x4 __attribute__((ext_vector_type(4)));
typedef uint32_t u32x2 __attribute__((ext_vector_type(2)));
typedef __fp16   h2_t  __attribute__((ext_vector_type(2)));

__device__ __forceinline__ uint32_t pkrtz(float a, float b) {
  h2_t h = __builtin_amdgcn_cvt_pkrtz(a, b);
  return __builtin_bit_cast(uint32_t, h);
}
__device__ __forceinline__ f32x4 mfma16(u32x4 a, u32x4 b, f32x4 c) {
  return __builtin_amdgcn_mfma_f32_16x16x32_f16(
      __builtin_bit_cast(half8, a), __builtin_bit_cast(half8, b), c, 0, 0, 0);
}
__device__ __forceinline__ u32x4 relu_pack(f32x4 lo, f32x4 hi) {
  u32x4 t = { pkrtz(fmaxf(lo[0],0.f), fmaxf(lo[1],0.f)),
              pkrtz(fmaxf(lo[2],0.f), fmaxf(lo[3],0.f)),
              pkrtz(fmaxf(hi[0],0.f), fmaxf(hi[1],0.f)),
              pkrtz(fmaxf(hi[2],0.f), fmaxf(hi[3],0.f)) };
  return t;
}

// ---- pack W^T -> A-fragment layout (HW-verified R4), LDS-staged ----
__global__ __launch_bounds__(256) void pack_w2(
    const float* __restrict__ W1, const float* __restrict__ W2,
    const float* __restrict__ W3, uint32_t* __restrict__ ws) {
  __shared__ float wt[DD*DD];
  const int blk = blockIdx.x;
  const int e = blk >> 1, half = blk & 1;
  const float* Wsrc = (half ? W2 : W1) + (size_t)e*DD*DD;
  const float4* s4 = (const float4*)Wsrc;
  float4* d4 = (float4*)wt;
  #pragma unroll
  for (int i = 0; i < DD*DD/4/256; ++i)
    d4[i*256 + threadIdx.x] = s4[i*256 + threadIdx.x];
  __syncthreads();

  for (int idx = threadIdx.x; idx < 8*64; idx += 256) {
    const int fl = idx >> 6, l = idx & 63;
    const int nt = fl >> 1, ks = fl & 1;
    const int n  = nt*16 + (l & 15), g = l >> 4;
    uint32_t dst[4];
    #pragma unroll
    for (int d = 0; d < 4; ++d) {
      float v[2];
      #pragma unroll
      for (int h = 0; h < 2; ++h) {
        const int kk = 16*(d>>1) + 4*g + 2*(d&1) + h;
        v[h] = wt[(32*ks + kk)*DD + n];
      }
      dst[d] = pkrtz(v[0], v[1]);
    }
    uint32_t* p = ws + ((size_t)(e*NFRAG + half*8 + fl)*64 + l)*4;
    p[0]=dst[0]; p[1]=dst[1]; p[2]=dst[2]; p[3]=dst[3];
  }
  if (half == 0) {
    const float* Wl2 = W3 + (size_t)e*DD*NDC;
    for (int idx = threadIdx.x; idx < 2*64; idx += 256) {
      const int ks = idx >> 6, l = idx & 63;
      const int n  = l & 15, g = l >> 4;
      uint32_t dst[4];
      #pragma unroll
      for (int d = 0; d < 4; ++d) {
        float v[2];
        #pragma unroll
        for (int h = 0; h < 2; ++h) {
          const int kk = 16*(d>>1) + 4*g + 2*(d&1) + h;
          v[h] = (n < NDC) ? Wl2[(32*ks + kk)*NDC + n] : 0.0f;
        }
        dst[d] = pkrtz(v[0], v[1]);
      }
      uint32_t* p = ws + ((size_t)(e*NFRAG + 16 + ks)*64 + l)*4;
      p[0]=dst[0]; p[1]=dst[1]; p[2]=dst[2]; p[3]=dst[3];
    }
  }
}

// ---- fused: one expert per wave (7 waves); shuffle scan; direct stores ----
__global__ __launch_bounds__(BLOCK, 2) void fused(
    const float* __restrict__ X, const int* __restrict__ S,
    const u32x4* __restrict__ wf,
    const float* __restrict__ b1, const float* __restrict__ b2,
    const float* __restrict__ b3,
    float* __restrict__ out, int B)
{
  __shared__ uint32_t pk[ROWS*32];     // 32 KB packed fp16 X, slot-swizzled
  __shared__ uint16_t srt[ROWS];
  __shared__ int wcnt[4][NE], woff[4][NE], cnt[NE];

  const int tid  = threadIdx.x;
  const int wv   = tid >> 6, lane = tid & 63;
  const int r15  = lane & 15, g = lane >> 4;
  const int base = blockIdx.x * ROWS;
  const int e    = wv;                 // wave = expert, exactly one each

  // ---- issue order: S (heads the dependent ballot chain) -> af -> X ----
  int e_i = 0;
  if (wv < 4) e_i = S[base + tid];

  u32x4 af[NFRAG];
  {
    const u32x4* wse = wf + (size_t)e*NFRAG*64;
    #pragma unroll
    for (int f = 0; f < NFRAG; ++f) af[f] = wse[f*64 + lane];
  }

  // ---- B: X -> pk (grid-stride over 4096 float4), fp16 pack, slot-swizzle ----
  {
    const float4* Xb = (const float4*)(X + (size_t)base * DD);
    for (int i = tid; i < ROWS*16; i += BLOCK) {
      const int r = i >> 4, q = i & 15;
      const float4 v = Xb[i];
      const int slotq = 4*(q >> 3) + (q & 3);
      const int hq    = (q >> 2) & 1;
      u32x2 w2 = { pkrtz(v.x, v.y), pkrtz(v.z, v.w) };
      *(u32x2*)&pk[r*32 + ((slotq ^ (r & 7)) << 2) + hq*2] = w2;
    }
  }

  // ---- A1: route ballots (waves 0-3 own the 256 rows) ----
  int myprefix = 0;
  if (wv < 4) {
    unsigned long long mk[NE];
    #pragma unroll
    for (int q2 = 0; q2 < NE; ++q2) mk[q2] = __ballot(e_i == q2);
    #pragma unroll
    for (int q2 = 0; q2 < NE; ++q2)
      if (e_i == q2) myprefix = __popcll(mk[q2] & ((1ull << lane) - 1ull));
    if (lane < NE) wcnt[wv][lane] = __popcll(mk[lane]);
  }
  __syncthreads();

  // ---- A2: wave-0 shuffle prefix scan over 28 (e,w) counts (i = e*4 + w) ----
  if (wv == 0) {
    const int i = lane;
    int v = (i < 4*NE) ? wcnt[i & 3][i >> 2] : 0;
    int incl = v;
    #pragma unroll
    for (int d2 = 1; d2 < 32; d2 <<= 1) {
      const int t2 = __shfl_up(incl, d2, 64);
      if (lane >= d2) incl += t2;
    }
    const int excl = incl - v;
    if (i < 4*NE) woff[i & 3][i >> 2] = excl;
    const int incl3 = __shfl(incl, 4*lane + 3, 64);
    const int excl0 = __shfl(excl, 4*lane,     64);
    if (i < NE) cnt[i] = incl3 - excl0;
  }
  __syncthreads();

  // ---- A3: scatter sorted list ----
  if (wv < 4) srt[woff[wv][e_i] + myprefix] = (uint16_t)tid;
  __syncthreads();

  // ---- C: this wave's single expert; register-resident subpasses; direct stores ----
  {
    const int cn    = cnt[e];
    const int sbase = woff[0][e];
    const float4 bv1[4] = { *(const float4*)(b1 + e*DD +  0 + 4*g),
                            *(const float4*)(b1 + e*DD + 16 + 4*g),
                            *(const float4*)(b1 + e*DD + 32 + 4*g),
                            *(const float4*)(b1 + e*DD + 48 + 4*g) };
    const float4 bv2[4] = { *(const float4*)(b2 + e*DD +  0 + 4*g),
                            *(const float4*)(b2 + e*DD + 16 + 4*g),
                            *(const float4*)(b2 + e*DD + 32 + 4*g),
                            *(const float4*)(b2 + e*DD + 48 + 4*g) };
    const float bb0 = b3[e*NDC+0], bb1 = b3[e*NDC+1], bb2 = b3[e*NDC+2];

    for (int r0 = 0; r0 < cn; r0 += 16) {
      const int m  = cn - r0;
      const int lr = srt[sbase + r0 + min(r15, m - 1)];

      const u32x4 xf0 = *(const u32x4*)&pk[lr*32 + (((    g) ^ (lr & 7)) << 2)];
      const u32x4 xf1 = *(const u32x4*)&pk[lr*32 + (((4 + g) ^ (lr & 7)) << 2)];

      f32x4 c[4];
      #pragma unroll
      for (int nt = 0; nt < 4; ++nt) {
        f32x4 acc = { bv1[nt].x, bv1[nt].y, bv1[nt].z, bv1[nt].w };
        acc = mfma16(af[nt*2 + 0], xf0, acc);
        acc = mfma16(af[nt*2 + 1], xf1, acc);
        c[nt] = acc;
      }
      const u32x4 h0 = relu_pack(c[0], c[1]);
      const u32x4 h1 = relu_pack(c[2], c[3]);

      #pragma unroll
      for (int nt = 0; nt < 4; ++nt) {
        f32x4 acc = { bv2[nt].x, bv2[nt].y, bv2[nt].z, bv2[nt].w };
        acc = mfma16(af[8 + nt*2 + 0], h0, acc);
        acc = mfma16(af[8 + nt*2 + 1], h1, acc);
        c[nt] = acc;
      }
      const u32x4 t0 = relu_pack(c[0], c[1]);
      const u32x4 t1 = relu_pack(c[2], c[3]);

      f32x4 acc = { bb0, bb1, bb2, 0.f };
      acc = mfma16(af[16], t0, acc);
      acc = mfma16(af[17], t1, acc);

      if (g == 0 && r15 < m) {
        const int row = base + lr;
        const float l0 = acc[0], l1 = acc[1], l2 = acc[2];
        const float mx  = fmaxf(l0, fmaxf(l1, l2));
        const float p0  = __expf(l0 - mx);
        const float p1  = __expf(l1 - mx);
        const float p2  = __expf(l2 - mx);
        const float inv = 1.0f / (p0 + p1 + p2);
        float* o = out + (size_t)row*3;
        o[0] = l0; o[1] = l1; o[2] = l2;
        float* pr = out + (size_t)B*3 + (size_t)row*3;
        pr[0] = p0*inv; pr[1] = p1*inv; pr[2] = p2*inv;
      }
    }
  }
}

extern "C" void kernel_launch(void* const* d_in, const int* in_sizes, int n_in,
                              void* d_out, int out_size, void* d_ws, size_t ws_size,
                              hipStream_t stream)
{
  const float* X  = (const float*)d_in[0];
  const int*   S  = (const int*)d_in[1];
  const float* W1 = (const float*)d_in[2];
  const float* B1 = (const float*)d_in[3];
  const float* W2 = (const float*)d_in[4];
  const float* B2 = (const float*)d_in[5];
  const float* W3 = (const float*)d_in[6];
  const float* B3 = (const float*)d_in[7];
  float* out = (float*)d_out;
  uint32_t* ws = (uint32_t*)d_ws;

  const int B = in_sizes[0] / DD;   // 262144

  pack_w2<<<NE*2, 256, 0, stream>>>(W1, W2, W3, ws);
  fused<<<B / ROWS, BLOCK, 0, stream>>>(X, S, (const u32x4*)ws,
                                        B1, B2, B3, out, B);
}

// Round 23
// 36.365 us; speedup vs baseline: 1.0579x; 1.0579x over previous
//
#include <hip/hip_runtime.h>
#include <stdint.h>

#define NE    7
#define DD    64
#define NDC   3
#define BLOCK 256
#define ROWS  256       // rows per block; B = 1024*256
#define NFRAG 18

typedef __fp16   half8 __attribute__((ext_vector_type(8)));
typedef float    f32x4 __attribute__((ext_vector_type(4)));
typedef uint32_t u32x4 __attribute__((ext_vector_type(4)));
typedef __fp16   h2_t  __attribute__((ext_vector_type(2)));

__device__ __forceinline__ uint32_t pkrtz(float a, float b) {
  h2_t h = __builtin_amdgcn_cvt_pkrtz(a, b);
  return __builtin_bit_cast(uint32_t, h);
}
__device__ __forceinline__ f32x4 mfma16(u32x4 a, u32x4 b, f32x4 c) {
  return __builtin_amdgcn_mfma_f32_16x16x32_f16(
      __builtin_bit_cast(half8, a), __builtin_bit_cast(half8, b), c, 0, 0, 0);
}
__device__ __forceinline__ u32x4 relu_pack(f32x4 lo, f32x4 hi) {
  u32x4 t = { pkrtz(fmaxf(lo[0],0.f), fmaxf(lo[1],0.f)),
              pkrtz(fmaxf(lo[2],0.f), fmaxf(lo[3],0.f)),
              pkrtz(fmaxf(hi[0],0.f), fmaxf(hi[1],0.f)),
              pkrtz(fmaxf(hi[2],0.f), fmaxf(hi[3],0.f)) };
  return t;
}

// ---- pack W^T -> A-fragment layout (HW-verified R4), LDS-staged ----
__global__ __launch_bounds__(256) void pack_w2(
    const float* __restrict__ W1, const float* __restrict__ W2,
    const float* __restrict__ W3, uint32_t* __restrict__ ws) {
  __shared__ float wt[DD*DD];
  const int blk = blockIdx.x;
  const int e = blk >> 1, half = blk & 1;
  const float* Wsrc = (half ? W2 : W1) + (size_t)e*DD*DD;
  const float4* s4 = (const float4*)Wsrc;
  float4* d4 = (float4*)wt;
  #pragma unroll
  for (int i = 0; i < DD*DD/4/256; ++i)
    d4[i*256 + threadIdx.x] = s4[i*256 + threadIdx.x];
  __syncthreads();

  for (int idx = threadIdx.x; idx < 8*64; idx += 256) {
    const int fl = idx >> 6, l = idx & 63;
    const int nt = fl >> 1, ks = fl & 1;
    const int n  = nt*16 + (l & 15), g = l >> 4;
    uint32_t dst[4];
    #pragma unroll
    for (int d = 0; d < 4; ++d) {
      float v[2];
      #pragma unroll
      for (int h = 0; h < 2; ++h) {
        const int kk = 16*(d>>1) + 4*g + 2*(d&1) + h;
        v[h] = wt[(32*ks + kk)*DD + n];
      }
      dst[d] = pkrtz(v[0], v[1]);
    }
    uint32_t* p = ws + ((size_t)(e*NFRAG + half*8 + fl)*64 + l)*4;
    p[0]=dst[0]; p[1]=dst[1]; p[2]=dst[2]; p[3]=dst[3];
  }
  if (half == 0) {
    const float* Wl2 = W3 + (size_t)e*DD*NDC;
    for (int idx = threadIdx.x; idx < 2*64; idx += 256) {
      const int ks = idx >> 6, l = idx & 63;
      const int n  = l & 15, g = l >> 4;
      uint32_t dst[4];
      #pragma unroll
      for (int d = 0; d < 4; ++d) {
        float v[2];
        #pragma unroll
        for (int h = 0; h < 2; ++h) {
          const int kk = 16*(d>>1) + 4*g + 2*(d&1) + h;
          v[h] = (n < NDC) ? Wl2[(32*ks + kk)*NDC + n] : 0.0f;
        }
        dst[d] = pkrtz(v[0], v[1]);
      }
      uint32_t* p = ws + ((size_t)(e*NFRAG + 16 + ks)*64 + l)*4;
      p[0]=dst[0]; p[1]=dst[1]; p[2]=dst[2]; p[3]=dst[3];
    }
  }
}

// ---- fused: no X staging (direct 64B-granule gather in C); tiny LDS ----
__global__ __launch_bounds__(BLOCK, 3) void fused(
    const float* __restrict__ X, const int* __restrict__ S,
    const u32x4* __restrict__ wf,
    const float* __restrict__ b1, const float* __restrict__ b2,
    const float* __restrict__ b3,
    float* __restrict__ out, int B)
{
  __shared__ uint16_t srt[ROWS];
  __shared__ int wcnt[4][NE], woff[4][NE], cnt[NE];

  const int tid  = threadIdx.x;
  const int wv   = tid >> 6, lane = tid & 63;
  const int r15  = lane & 15, g = lane >> 4;
  const int base = blockIdx.x * ROWS;

  // ---- issue order: S (heads the dependent ballot chain) -> af ----
  const int e_i = S[base + tid];

  u32x4 af[NFRAG];
  {
    const u32x4* wse = wf + (size_t)wv*NFRAG*64;
    #pragma unroll
    for (int f = 0; f < NFRAG; ++f) af[f] = wse[f*64 + lane];
  }

  // ---- A1: route ballots (each thread owns row tid) ----
  int myprefix = 0;
  {
    unsigned long long mk[NE];
    #pragma unroll
    for (int q2 = 0; q2 < NE; ++q2) mk[q2] = __ballot(e_i == q2);
    #pragma unroll
    for (int q2 = 0; q2 < NE; ++q2)
      if (e_i == q2) myprefix = __popcll(mk[q2] & ((1ull << lane) - 1ull));
    if (lane < NE) wcnt[wv][lane] = __popcll(mk[lane]);
  }
  __syncthreads();

  // ---- A2: wave-0 shuffle prefix scan over 28 (e,w) counts (i = e*4 + w) ----
  if (wv == 0) {
    const int i = lane;
    int v = (i < 4*NE) ? wcnt[i & 3][i >> 2] : 0;
    int incl = v;
    #pragma unroll
    for (int d2 = 1; d2 < 32; d2 <<= 1) {
      const int t2 = __shfl_up(incl, d2, 64);
      if (lane >= d2) incl += t2;
    }
    const int excl = incl - v;
    if (i < 4*NE) woff[i & 3][i >> 2] = excl;
    const int incl3 = __shfl(incl, 4*lane + 3, 64);
    const int excl0 = __shfl(excl, 4*lane,     64);
    if (i < NE) cnt[i] = incl3 - excl0;
  }
  __syncthreads();

  // ---- A3: scatter sorted list ----
  srt[woff[wv][e_i] + myprefix] = (uint16_t)tid;
  __syncthreads();

  // ---- C: wave-static experts; X gathered directly (16 rows x 64B segments) ----
  auto run_expert = [&](int e, const u32x4 (&A)[NFRAG]) {
    const int cn    = cnt[e];
    const int sbase = woff[0][e];
    const float4 bv1[4] = { *(const float4*)(b1 + e*DD +  0 + 4*g),
                            *(const float4*)(b1 + e*DD + 16 + 4*g),
                            *(const float4*)(b1 + e*DD + 32 + 4*g),
                            *(const float4*)(b1 + e*DD + 48 + 4*g) };
    const float4 bv2[4] = { *(const float4*)(b2 + e*DD +  0 + 4*g),
                            *(const float4*)(b2 + e*DD + 16 + 4*g),
                            *(const float4*)(b2 + e*DD + 32 + 4*g),
                            *(const float4*)(b2 + e*DD + 48 + 4*g) };
    const float bb0 = b3[e*NDC+0], bb1 = b3[e*NDC+1], bb2 = b3[e*NDC+2];

    for (int r0 = 0; r0 < cn; r0 += 16) {
      const int m  = cn - r0;
      const int lr = srt[sbase + r0 + min(r15, m - 1)];

      // direct gather: 4 lanes per row x 16B contiguous = 64B native segments
      const float* xr = X + (size_t)(base + lr)*DD;
      const float4 v00 = *(const float4*)(xr +      4*g);
      const float4 v01 = *(const float4*)(xr + 16 + 4*g);
      const float4 v10 = *(const float4*)(xr + 32 + 4*g);
      const float4 v11 = *(const float4*)(xr + 48 + 4*g);
      const u32x4 xf0 = { pkrtz(v00.x,v00.y), pkrtz(v00.z,v00.w),
                          pkrtz(v01.x,v01.y), pkrtz(v01.z,v01.w) };
      const u32x4 xf1 = { pkrtz(v10.x,v10.y), pkrtz(v10.z,v10.w),
                          pkrtz(v11.x,v11.y), pkrtz(v11.z,v11.w) };

      f32x4 c[4];
      #pragma unroll
      for (int nt = 0; nt < 4; ++nt) {
        f32x4 acc = { bv1[nt].x, bv1[nt].y, bv1[nt].z, bv1[nt].w };
        acc = mfma16(A[nt*2 + 0], xf0, acc);
        acc = mfma16(A[nt*2 + 1], xf1, acc);
        c[nt] = acc;
      }
      const u32x4 h0 = relu_pack(c[0], c[1]);
      const u32x4 h1 = relu_pack(c[2], c[3]);

      #pragma unroll
      for (int nt = 0; nt < 4; ++nt) {
        f32x4 acc = { bv2[nt].x, bv2[nt].y, bv2[nt].z, bv2[nt].w };
        acc = mfma16(A[8 + nt*2 + 0], h0, acc);
        acc = mfma16(A[8 + nt*2 + 1], h1, acc);
        c[nt] = acc;
      }
      const u32x4 t0 = relu_pack(c[0], c[1]);
      const u32x4 t1 = relu_pack(c[2], c[3]);

      f32x4 acc = { bb0, bb1, bb2, 0.f };
      acc = mfma16(A[16], t0, acc);
      acc = mfma16(A[17], t1, acc);

      if (g == 0 && r15 < m) {
        const int row = base + lr;
        const float l0 = acc[0], l1 = acc[1], l2 = acc[2];
        const float mx  = fmaxf(l0, fmaxf(l1, l2));
        const float p0  = __expf(l0 - mx);
        const float p1  = __expf(l1 - mx);
        const float p2  = __expf(l2 - mx);
        const float inv = 1.0f / (p0 + p1 + p2);
        float* o = out + (size_t)row*3;
        o[0] = l0; o[1] = l1; o[2] = l2;
        float* pr = out + (size_t)B*3 + (size_t)row*3;
        pr[0] = p0*inv; pr[1] = p1*inv; pr[2] = p2*inv;
      }
    }
  };

  run_expert(wv, af);

  if (wv < 3) {
    const int e2 = wv + 4;
    const u32x4* wse2 = wf + (size_t)e2*NFRAG*64;
    #pragma unroll
    for (int f = 0; f < NFRAG; ++f) af[f] = wse2[f*64 + lane];   // one exposed reload
    run_expert(e2, af);
  }
}

extern "C" void kernel_launch(void* const* d_in, const int* in_sizes, int n_in,
                              void* d_out, int out_size, void* d_ws, size_t ws_size,
                              hipStream_t stream)
{
  const float* X  = (const float*)d_in[0];
  const int*   S  = (const int*)d_in[1];
  const float* W1 = (const float*)d_in[2];
  const float* B1 = (const float*)d_in[3];
  const float* W2 = (const float*)d_in[4];
  const float* B2 = (const float*)d_in[5];
  const float* W3 = (const float*)d_in[6];
  const float* B3 = (const float*)d_in[7];
  float* out = (float*)d_out;
  uint32_t* ws = (uint32_t*)d_ws;

  const int B = in_sizes[0] / DD;   // 262144

  pack_w2<<<NE*2, 256, 0, stream>>>(W1, W2, W3, ws);
  fused<<<B / ROWS, BLOCK, 0, stream>>>(X, S, (const u32x4*)ws,
                                        B1, B2, B3, out, B);
}

// Round 24
// 32.459 us; speedup vs baseline: 1.1851x; 1.1203x over previous
//
#include <hip/hip_runtime.h>
#include <stdint.h>

#define NE    7
#define DD    64
#define NDC   3
#define BLOCK 256
#define ROWS  256       // rows per block; B = 1024*256
#define NFRAG 18

typedef __fp16   half8 __attribute__((ext_vector_type(8)));
typedef float    f32x4 __attribute__((ext_vector_type(4)));
typedef uint32_t u32x4 __attribute__((ext_vector_type(4)));
typedef uint32_t u32x2 __attribute__((ext_vector_type(2)));
typedef __fp16   h2_t  __attribute__((ext_vector_type(2)));

__device__ __forceinline__ uint32_t pkrtz(float a, float b) {
  h2_t h = __builtin_amdgcn_cvt_pkrtz(a, b);
  return __builtin_bit_cast(uint32_t, h);
}
__device__ __forceinline__ f32x4 mfma16(u32x4 a, u32x4 b, f32x4 c) {
  return __builtin_amdgcn_mfma_f32_16x16x32_f16(
      __builtin_bit_cast(half8, a), __builtin_bit_cast(half8, b), c, 0, 0, 0);
}
__device__ __forceinline__ u32x4 relu_pack(f32x4 lo, f32x4 hi) {
  u32x4 t = { pkrtz(fmaxf(lo[0],0.f), fmaxf(lo[1],0.f)),
              pkrtz(fmaxf(lo[2],0.f), fmaxf(lo[3],0.f)),
              pkrtz(fmaxf(hi[0],0.f), fmaxf(hi[1],0.f)),
              pkrtz(fmaxf(hi[2],0.f), fmaxf(hi[3],0.f)) };
  return t;
}

// ---- pack W^T -> A-fragment layout (HW-verified R4), LDS-staged ----
__global__ __launch_bounds__(256) void pack_w2(
    const float* __restrict__ W1, const float* __restrict__ W2,
    const float* __restrict__ W3, uint32_t* __restrict__ ws) {
  __shared__ float wt[DD*DD];
  const int blk = blockIdx.x;
  const int e = blk >> 1, half = blk & 1;
  const float* Wsrc = (half ? W2 : W1) + (size_t)e*DD*DD;
  const float4* s4 = (const float4*)Wsrc;
  float4* d4 = (float4*)wt;
  #pragma unroll
  for (int i = 0; i < DD*DD/4/256; ++i)
    d4[i*256 + threadIdx.x] = s4[i*256 + threadIdx.x];
  __syncthreads();

  for (int idx = threadIdx.x; idx < 8*64; idx += 256) {
    const int fl = idx >> 6, l = idx & 63;
    const int nt = fl >> 1, ks = fl & 1;
    const int n  = nt*16 + (l & 15), g = l >> 4;
    uint32_t dst[4];
    #pragma unroll
    for (int d = 0; d < 4; ++d) {
      float v[2];
      #pragma unroll
      for (int h = 0; h < 2; ++h) {
        const int kk = 16*(d>>1) + 4*g + 2*(d&1) + h;
        v[h] = wt[(32*ks + kk)*DD + n];
      }
      dst[d] = pkrtz(v[0], v[1]);
    }
    uint32_t* p = ws + ((size_t)(e*NFRAG + half*8 + fl)*64 + l)*4;
    p[0]=dst[0]; p[1]=dst[1]; p[2]=dst[2]; p[3]=dst[3];
  }
  if (half == 0) {
    const float* Wl2 = W3 + (size_t)e*DD*NDC;
    for (int idx = threadIdx.x; idx < 2*64; idx += 256) {
      const int ks = idx >> 6, l = idx & 63;
      const int n  = l & 15, g = l >> 4;
      uint32_t dst[4];
      #pragma unroll
      for (int d = 0; d < 4; ++d) {
        float v[2];
        #pragma unroll
        for (int h = 0; h < 2; ++h) {
          const int kk = 16*(d>>1) + 4*g + 2*(d&1) + h;
          v[h] = (n < NDC) ? Wl2[(32*ks + kk)*NDC + n] : 0.0f;
        }
        dst[d] = pkrtz(v[0], v[1]);
      }
      uint32_t* p = ws + ((size_t)(e*NFRAG + 16 + ks)*64 + l)*4;
      p[0]=dst[0]; p[1]=dst[1]; p[2]=dst[2]; p[3]=dst[3];
    }
  }
}

// ---- fused: wave-static experts, BOTH fragment sets resident from entry ----
__global__ __launch_bounds__(BLOCK, 2) void fused(
    const float* __restrict__ X, const int* __restrict__ S,
    const u32x4* __restrict__ wf,
    const float* __restrict__ b1, const float* __restrict__ b2,
    const float* __restrict__ b3,
    float* __restrict__ out, int B)
{
  __shared__ uint32_t pk[ROWS*32];     // 32 KB packed fp16 X, slot-swizzled
  __shared__ uint16_t srt[ROWS];
  __shared__ int wcnt[4][NE], woff[4][NE], cnt[NE];

  const int tid  = threadIdx.x;
  const int wv   = tid >> 6, lane = tid & 63;
  const int r15  = lane & 15, g = lane >> 4;
  const int base = blockIdx.x * ROWS;

  // ---- issue order: S (heads the dependent ballot chain) -> afA+afB -> X ----
  const int e_i = S[base + tid];

  u32x4 afA[NFRAG], afB[NFRAG];
  {
    const u32x4* wsa = wf + (size_t)wv*NFRAG*64;
    const u32x4* wsb = wf + (size_t)((wv < 3) ? wv + 4 : 6)*NFRAG*64;
    #pragma unroll
    for (int f = 0; f < NFRAG; ++f) afA[f] = wsa[f*64 + lane];
    #pragma unroll
    for (int f = 0; f < NFRAG; ++f) afB[f] = wsb[f*64 + lane];
  }

  // ---- B: X -> pk (4-KB contiguous per block-instr), fp16 pack, slot-swizzle ----
  {
    const float4* Xb = (const float4*)(X + (size_t)base * DD);
    #pragma unroll
    for (int it = 0; it < 16; ++it) {
      const int i = it*BLOCK + tid;
      const int r = i >> 4, q = i & 15;
      const float4 v = Xb[i];
      const int slotq = 4*(q >> 3) + (q & 3);
      const int hq    = (q >> 2) & 1;
      u32x2 w2 = { pkrtz(v.x, v.y), pkrtz(v.z, v.w) };
      *(u32x2*)&pk[r*32 + ((slotq ^ (r & 7)) << 2) + hq*2] = w2;
    }
  }

  // ---- A1: route ballots (each thread owns row tid) ----
  int myprefix = 0;
  {
    unsigned long long mk[NE];
    #pragma unroll
    for (int q2 = 0; q2 < NE; ++q2) mk[q2] = __ballot(e_i == q2);
    #pragma unroll
    for (int q2 = 0; q2 < NE; ++q2)
      if (e_i == q2) myprefix = __popcll(mk[q2] & ((1ull << lane) - 1ull));
    if (lane < NE) wcnt[wv][lane] = __popcll(mk[lane]);
  }
  __syncthreads();

  // ---- A2: wave-0 shuffle prefix scan over 28 (e,w) counts (i = e*4 + w) ----
  if (wv == 0) {
    const int i = lane;
    int v = (i < 4*NE) ? wcnt[i & 3][i >> 2] : 0;
    int incl = v;
    #pragma unroll
    for (int d2 = 1; d2 < 32; d2 <<= 1) {
      const int t2 = __shfl_up(incl, d2, 64);
      if (lane >= d2) incl += t2;
    }
    const int excl = incl - v;
    if (i < 4*NE) woff[i & 3][i >> 2] = excl;
    const int incl3 = __shfl(incl, 4*lane + 3, 64);
    const int excl0 = __shfl(excl, 4*lane,     64);
    if (i < NE) cnt[i] = incl3 - excl0;
  }
  __syncthreads();

  // ---- A3: scatter sorted list ----
  srt[woff[wv][e_i] + myprefix] = (uint16_t)tid;
  __syncthreads();

  // ---- C: wave-static experts (wv, then wv+4 for wv<3); zero weight stalls ----
  auto run_expert = [&](int e, const u32x4 (&A)[NFRAG]) {
    const int cn    = cnt[e];
    const int sbase = woff[0][e];
    const float4 bv1[4] = { *(const float4*)(b1 + e*DD +  0 + 4*g),
                            *(const float4*)(b1 + e*DD + 16 + 4*g),
                            *(const float4*)(b1 + e*DD + 32 + 4*g),
                            *(const float4*)(b1 + e*DD + 48 + 4*g) };
    const float4 bv2[4] = { *(const float4*)(b2 + e*DD +  0 + 4*g),
                            *(const float4*)(b2 + e*DD + 16 + 4*g),
                            *(const float4*)(b2 + e*DD + 32 + 4*g),
                            *(const float4*)(b2 + e*DD + 48 + 4*g) };
    const float bb0 = b3[e*NDC+0], bb1 = b3[e*NDC+1], bb2 = b3[e*NDC+2];

    for (int r0 = 0; r0 < cn; r0 += 16) {
      const int m  = cn - r0;
      const int lr = srt[sbase + r0 + min(r15, m - 1)];

      const u32x4 xf0 = *(const u32x4*)&pk[lr*32 + (((    g) ^ (lr & 7)) << 2)];
      const u32x4 xf1 = *(const u32x4*)&pk[lr*32 + (((4 + g) ^ (lr & 7)) << 2)];

      f32x4 c[4];
      #pragma unroll
      for (int nt = 0; nt < 4; ++nt) {
        f32x4 acc = { bv1[nt].x, bv1[nt].y, bv1[nt].z, bv1[nt].w };
        acc = mfma16(A[nt*2 + 0], xf0, acc);
        acc = mfma16(A[nt*2 + 1], xf1, acc);
        c[nt] = acc;
      }
      const u32x4 h0 = relu_pack(c[0], c[1]);
      const u32x4 h1 = relu_pack(c[2], c[3]);

      #pragma unroll
      for (int nt = 0; nt < 4; ++nt) {
        f32x4 acc = { bv2[nt].x, bv2[nt].y, bv2[nt].z, bv2[nt].w };
        acc = mfma16(A[8 + nt*2 + 0], h0, acc);
        acc = mfma16(A[8 + nt*2 + 1], h1, acc);
        c[nt] = acc;
      }
      const u32x4 t0 = relu_pack(c[0], c[1]);
      const u32x4 t1 = relu_pack(c[2], c[3]);

      f32x4 acc = { bb0, bb1, bb2, 0.f };
      acc = mfma16(A[16], t0, acc);
      acc = mfma16(A[17], t1, acc);

      if (g == 0 && r15 < m) {
        const int row = base + lr;
        const float l0 = acc[0], l1 = acc[1], l2 = acc[2];
        const float mx  = fmaxf(l0, fmaxf(l1, l2));
        const float p0  = __expf(l0 - mx);
        const float p1  = __expf(l1 - mx);
        const float p2  = __expf(l2 - mx);
        const float inv = 1.0f / (p0 + p1 + p2);
        float* o = out + (size_t)row*3;
        o[0] = l0; o[1] = l1; o[2] = l2;
        float* pr = out + (size_t)B*3 + (size_t)row*3;
        pr[0] = p0*inv; pr[1] = p1*inv; pr[2] = p2*inv;
      }
    }
  };

  run_expert(wv, afA);
  if (wv < 3) run_expert(wv + 4, afB);
}

extern "C" void kernel_launch(void* const* d_in, const int* in_sizes, int n_in,
                              void* d_out, int out_size, void* d_ws, size_t ws_size,
                              hipStream_t stream)
{
  const float* X  = (const float*)d_in[0];
  const int*   S  = (const int*)d_in[1];
  const float* W1 = (const float*)d_in[2];
  const float* B1 = (const float*)d_in[3];
  const float* W2 = (const float*)d_in[4];
  const float* B2 = (const float*)d_in[5];
  const float* W3 = (const float*)d_in[6];
  const float* B3 = (const float*)d_in[7];
  float* out = (float*)d_out;
  uint32_t* ws = (uint32_t*)d_ws;

  const int B = in_sizes[0] / DD;   // 262144

  pack_w2<<<NE*2, 256, 0, stream>>>(W1, W2, W3, ws);
  fused<<<B / ROWS, BLOCK, 0, stream>>>(X, S, (const u32x4*)ws,
                                        B1, B2, B3, out, B);
}

// Round 25
// 29.526 us; speedup vs baseline: 1.3029x; 1.0994x over previous
//
#include <hip/hip_runtime.h>
#include <stdint.h>

#define NE    7
#define DD    64
#define NDC   3
#define BLOCK 256
#define ROWS  256       // rows per block; B = 1024*256
#define NFRAG 18

typedef __fp16   half8 __attribute__((ext_vector_type(8)));
typedef float    f32x4 __attribute__((ext_vector_type(4)));
typedef uint32_t u32x4 __attribute__((ext_vector_type(4)));
typedef uint32_t u32x2 __attribute__((ext_vector_type(2)));
typedef __fp16   h2_t  __attribute__((ext_vector_type(2)));

__device__ __forceinline__ uint32_t pkrtz(float a, float b) {
  h2_t h = __builtin_amdgcn_cvt_pkrtz(a, b);
  return __builtin_bit_cast(uint32_t, h);
}
__device__ __forceinline__ f32x4 mfma16(u32x4 a, u32x4 b, f32x4 c) {
  return __builtin_amdgcn_mfma_f32_16x16x32_f16(
      __builtin_bit_cast(half8, a), __builtin_bit_cast(half8, b), c, 0, 0, 0);
}
__device__ __forceinline__ u32x4 relu_pack(f32x4 lo, f32x4 hi) {
  u32x4 t = { pkrtz(fmaxf(lo[0],0.f), fmaxf(lo[1],0.f)),
              pkrtz(fmaxf(lo[2],0.f), fmaxf(lo[3],0.f)),
              pkrtz(fmaxf(hi[0],0.f), fmaxf(hi[1],0.f)),
              pkrtz(fmaxf(hi[2],0.f), fmaxf(hi[3],0.f)) };
  return t;
}

// ---- pack W^T -> A-fragment layout (HW-verified R4), LDS-staged ----
__global__ __launch_bounds__(256) void pack_w2(
    const float* __restrict__ W1, const float* __restrict__ W2,
    const float* __restrict__ W3, uint32_t* __restrict__ ws) {
  __shared__ float wt[DD*DD];
  const int blk = blockIdx.x;
  const int e = blk >> 1, half = blk & 1;
  const float* Wsrc = (half ? W2 : W1) + (size_t)e*DD*DD;
  const float4* s4 = (const float4*)Wsrc;
  float4* d4 = (float4*)wt;
  #pragma unroll
  for (int i = 0; i < DD*DD/4/256; ++i)
    d4[i*256 + threadIdx.x] = s4[i*256 + threadIdx.x];
  __syncthreads();

  for (int idx = threadIdx.x; idx < 8*64; idx += 256) {
    const int fl = idx >> 6, l = idx & 63;
    const int nt = fl >> 1, ks = fl & 1;
    const int n  = nt*16 + (l & 15), g = l >> 4;
    uint32_t dst[4];
    #pragma unroll
    for (int d = 0; d < 4; ++d) {
      float v[2];
      #pragma unroll
      for (int h = 0; h < 2; ++h) {
        const int kk = 16*(d>>1) + 4*g + 2*(d&1) + h;
        v[h] = wt[(32*ks + kk)*DD + n];
      }
      dst[d] = pkrtz(v[0], v[1]);
    }
    uint32_t* p = ws + ((size_t)(e*NFRAG + half*8 + fl)*64 + l)*4;
    p[0]=dst[0]; p[1]=dst[1]; p[2]=dst[2]; p[3]=dst[3];
  }
  if (half == 0) {
    const float* Wl2 = W3 + (size_t)e*DD*NDC;
    for (int idx = threadIdx.x; idx < 2*64; idx += 256) {
      const int ks = idx >> 6, l = idx & 63;
      const int n  = l & 15, g = l >> 4;
      uint32_t dst[4];
      #pragma unroll
      for (int d = 0; d < 4; ++d) {
        float v[2];
        #pragma unroll
        for (int h = 0; h < 2; ++h) {
          const int kk = 16*(d>>1) + 4*g + 2*(d&1) + h;
          v[h] = (n < NDC) ? Wl2[(32*ks + kk)*NDC + n] : 0.0f;
        }
        dst[d] = pkrtz(v[0], v[1]);
      }
      uint32_t* p = ws + ((size_t)(e*NFRAG + 16 + ks)*64 + l)*4;
      p[0]=dst[0]; p[1]=dst[1]; p[2]=dst[2]; p[3]=dst[3];
    }
  }
}

// ---- fused: wave-static experts; shuffle scan; direct stores (R21 verbatim) ----
__global__ __launch_bounds__(BLOCK, 3) void fused(
    const float* __restrict__ X, const int* __restrict__ S,
    const u32x4* __restrict__ wf,
    const float* __restrict__ b1, const float* __restrict__ b2,
    const float* __restrict__ b3,
    float* __restrict__ out, int B)
{
  __shared__ uint32_t pk[ROWS*32];     // 32 KB packed fp16 X, slot-swizzled
  __shared__ uint16_t srt[ROWS];
  __shared__ int wcnt[4][NE], woff[4][NE], cnt[NE];

  const int tid  = threadIdx.x;
  const int wv   = tid >> 6, lane = tid & 63;
  const int r15  = lane & 15, g = lane >> 4;
  const int base = blockIdx.x * ROWS;

  // ---- issue order: S (heads the dependent ballot chain) -> af -> X ----
  const int e_i = S[base + tid];

  u32x4 af[NFRAG];
  {
    const u32x4* wse = wf + (size_t)wv*NFRAG*64;
    #pragma unroll
    for (int f = 0; f < NFRAG; ++f) af[f] = wse[f*64 + lane];
  }

  // ---- B: X -> pk (4-KB contiguous per block-instr), fp16 pack, slot-swizzle ----
  {
    const float4* Xb = (const float4*)(X + (size_t)base * DD);
    #pragma unroll
    for (int it = 0; it < 16; ++it) {
      const int i = it*BLOCK + tid;
      const int r = i >> 4, q = i & 15;
      const float4 v = Xb[i];
      const int slotq = 4*(q >> 3) + (q & 3);
      const int hq    = (q >> 2) & 1;
      u32x2 w2 = { pkrtz(v.x, v.y), pkrtz(v.z, v.w) };
      *(u32x2*)&pk[r*32 + ((slotq ^ (r & 7)) << 2) + hq*2] = w2;
    }
  }

  // ---- A1: route ballots (each thread owns row tid) ----
  int myprefix = 0;
  {
    unsigned long long mk[NE];
    #pragma unroll
    for (int q2 = 0; q2 < NE; ++q2) mk[q2] = __ballot(e_i == q2);
    #pragma unroll
    for (int q2 = 0; q2 < NE; ++q2)
      if (e_i == q2) myprefix = __popcll(mk[q2] & ((1ull << lane) - 1ull));
    if (lane < NE) wcnt[wv][lane] = __popcll(mk[lane]);
  }
  __syncthreads();

  // ---- A2: wave-0 shuffle prefix scan over 28 (e,w) counts (i = e*4 + w) ----
  if (wv == 0) {
    const int i = lane;
    int v = (i < 4*NE) ? wcnt[i & 3][i >> 2] : 0;
    int incl = v;
    #pragma unroll
    for (int d2 = 1; d2 < 32; d2 <<= 1) {
      const int t2 = __shfl_up(incl, d2, 64);
      if (lane >= d2) incl += t2;
    }
    const int excl = incl - v;
    if (i < 4*NE) woff[i & 3][i >> 2] = excl;
    const int incl3 = __shfl(incl, 4*lane + 3, 64);
    const int excl0 = __shfl(excl, 4*lane,     64);
    if (i < NE) cnt[i] = incl3 - excl0;
  }
  __syncthreads();

  // ---- A3: scatter sorted list ----
  srt[woff[wv][e_i] + myprefix] = (uint16_t)tid;
  __syncthreads();

  // ---- C: wave-static experts (wv, then wv+4 for wv<3); direct global stores ----
  auto run_expert = [&](int e, const u32x4 (&A)[NFRAG]) {
    const int cn    = cnt[e];
    const int sbase = woff[0][e];
    const float4 bv1[4] = { *(const float4*)(b1 + e*DD +  0 + 4*g),
                            *(const float4*)(b1 + e*DD + 16 + 4*g),
                            *(const float4*)(b1 + e*DD + 32 + 4*g),
                            *(const float4*)(b1 + e*DD + 48 + 4*g) };
    const float4 bv2[4] = { *(const float4*)(b2 + e*DD +  0 + 4*g),
                            *(const float4*)(b2 + e*DD + 16 + 4*g),
                            *(const float4*)(b2 + e*DD + 32 + 4*g),
                            *(const float4*)(b2 + e*DD + 48 + 4*g) };
    const float bb0 = b3[e*NDC+0], bb1 = b3[e*NDC+1], bb2 = b3[e*NDC+2];

    for (int r0 = 0; r0 < cn; r0 += 16) {
      const int m  = cn - r0;
      const int lr = srt[sbase + r0 + min(r15, m - 1)];

      const u32x4 xf0 = *(const u32x4*)&pk[lr*32 + (((    g) ^ (lr & 7)) << 2)];
      const u32x4 xf1 = *(const u32x4*)&pk[lr*32 + (((4 + g) ^ (lr & 7)) << 2)];

      f32x4 c[4];
      #pragma unroll
      for (int nt = 0; nt < 4; ++nt) {
        f32x4 acc = { bv1[nt].x, bv1[nt].y, bv1[nt].z, bv1[nt].w };
        acc = mfma16(A[nt*2 + 0], xf0, acc);
        acc = mfma16(A[nt*2 + 1], xf1, acc);
        c[nt] = acc;
      }
      const u32x4 h0 = relu_pack(c[0], c[1]);
      const u32x4 h1 = relu_pack(c[2], c[3]);

      #pragma unroll
      for (int nt = 0; nt < 4; ++nt) {
        f32x4 acc = { bv2[nt].x, bv2[nt].y, bv2[nt].z, bv2[nt].w };
        acc = mfma16(A[8 + nt*2 + 0], h0, acc);
        acc = mfma16(A[8 + nt*2 + 1], h1, acc);
        c[nt] = acc;
      }
      const u32x4 t0 = relu_pack(c[0], c[1]);
      const u32x4 t1 = relu_pack(c[2], c[3]);

      f32x4 acc = { bb0, bb1, bb2, 0.f };
      acc = mfma16(A[16], t0, acc);
      acc = mfma16(A[17], t1, acc);

      if (g == 0 && r15 < m) {
        const int row = base + lr;
        const float l0 = acc[0], l1 = acc[1], l2 = acc[2];
        const float mx  = fmaxf(l0, fmaxf(l1, l2));
        const float p0  = __expf(l0 - mx);
        const float p1  = __expf(l1 - mx);
        const float p2  = __expf(l2 - mx);
        const float inv = 1.0f / (p0 + p1 + p2);
        float* o = out + (size_t)row*3;
        o[0] = l0; o[1] = l1; o[2] = l2;
        float* pr = out + (size_t)B*3 + (size_t)row*3;
        pr[0] = p0*inv; pr[1] = p1*inv; pr[2] = p2*inv;
      }
    }
  };

  run_expert(wv, af);

  if (wv < 3) {
    const int e2 = wv + 4;
    const u32x4* wse2 = wf + (size_t)e2*NFRAG*64;
    #pragma unroll
    for (int f = 0; f < NFRAG; ++f) af[f] = wse2[f*64 + lane];   // one exposed reload
    run_expert(e2, af);
  }
}

extern "C" void kernel_launch(void* const* d_in, const int* in_sizes, int n_in,
                              void* d_out, int out_size, void* d_ws, size_t ws_size,
                              hipStream_t stream)
{
  const float* X  = (const float*)d_in[0];
  const int*   S  = (const int*)d_in[1];
  const float* W1 = (const float*)d_in[2];
  const float* B1 = (const float*)d_in[3];
  const float* W2 = (const float*)d_in[4];
  const float* B2 = (const float*)d_in[5];
  const float* W3 = (const float*)d_in[6];
  const float* B3 = (const float*)d_in[7];
  float* out = (float*)d_out;
  uint32_t* ws = (uint32_t*)d_ws;

  const int B = in_sizes[0] / DD;   // 262144

  pack_w2<<<NE*2, 256, 0, stream>>>(W1, W2, W3, ws);
  fused<<<B / ROWS, BLOCK, 0, stream>>>(X, S, (const u32x4*)ws,
                                        B1, B2, B3, out, B);
}